// Round 1
// baseline (11.675 us; speedup 1.0000x reference)
//
#include <hip/hip_runtime.h>
#include <hip/hip_bf16.h>

// Fused antialiased bilinear resize (2,3,345,456) -> (2,3,271,272), fp32.
// Horizontal: 456->272 (scale 456/272), Vertical: 345->271 (scale 345/271).
// Matches the aten decomposition: truncating int cast, clamp bounds, tap
// masking by window size (KSIZE=5), per-pixel weight normalization.

#define IW 456
#define IH 345
#define OW 272
#define OH 271
#define BC 6            // batch*channels = 2*3
#define KS 5

__global__ __launch_bounds__(256) void resize2d_kernel(
    const float* __restrict__ in, float* __restrict__ out)
{
    const int total = BC * OH * OW;
    int t = blockIdx.x * blockDim.x + threadIdx.x;
    if (t >= total) return;

    const int ox = t % OW;
    const int r  = t / OW;
    const int oy = r % OH;
    const int bc = r / OH;

    // ---- horizontal (x) weights ----
    const float scale_x = (float)IW / (float)OW;   // 1.6764706
    const float inv_x   = (float)OW / (float)IW;   // 0.59649123
    float cx = ((float)ox + 0.5f) * scale_x;
    int xmin = (int)(cx - scale_x + 0.5f);         // trunc toward zero == astype(int64)
    if (xmin < 0) xmin = 0;
    int xmax = (int)(cx + scale_x + 0.5f);
    if (xmax > IW) xmax = IW;
    int xsz = xmax - xmin; if (xsz > KS) xsz = KS;

    float wx[KS];
    float sx = 0.0f;
#pragma unroll
    for (int j = 0; j < KS; ++j) {
        float w = 1.0f - fminf(fabsf(((float)(j + xmin) - cx + 0.5f) * inv_x), 1.0f);
        w = (j < xsz) ? w : 0.0f;
        wx[j] = w;
        sx += w;
    }
#pragma unroll
    for (int j = 0; j < KS; ++j) wx[j] /= sx;

    // ---- vertical (y) weights ----
    const float scale_y = (float)IH / (float)OH;   // 1.2730627
    const float inv_y   = (float)OH / (float)IH;   // 0.78550725
    float cy = ((float)oy + 0.5f) * scale_y;
    int ymin = (int)(cy - scale_y + 0.5f);
    if (ymin < 0) ymin = 0;
    int ymax = (int)(cy + scale_y + 0.5f);
    if (ymax > IH) ymax = IH;
    int ysz = ymax - ymin; if (ysz > KS) ysz = KS;

    float wy[KS];
    float sy = 0.0f;
#pragma unroll
    for (int j = 0; j < KS; ++j) {
        float w = 1.0f - fminf(fabsf(((float)(j + ymin) - cy + 0.5f) * inv_y), 1.0f);
        w = (j < ysz) ? w : 0.0f;
        wy[j] = w;
        sy += w;
    }
#pragma unroll
    for (int j = 0; j < KS; ++j) wy[j] /= sy;

    // ---- gather + fused horizontal-then-vertical reduction ----
    const float* __restrict__ base = in + (size_t)bc * IH * IW;
    float acc = 0.0f;
#pragma unroll
    for (int jy = 0; jy < KS; ++jy) {
        int iy = jy + ymin; if (iy > IH - 1) iy = IH - 1;
        const float* __restrict__ row = base + (size_t)iy * IW;
        float h = 0.0f;
#pragma unroll
        for (int jx = 0; jx < KS; ++jx) {
            int ix = jx + xmin; if (ix > IW - 1) ix = IW - 1;
            h += row[ix] * wx[jx];
        }
        acc += h * wy[jy];
    }
    out[t] = acc;
}

extern "C" void kernel_launch(void* const* d_in, const int* in_sizes, int n_in,
                              void* d_out, int out_size, void* d_ws, size_t ws_size,
                              hipStream_t stream) {
    const float* in = (const float*)d_in[0];
    float* out = (float*)d_out;
    const int total = BC * OH * OW;   // 442272
    const int block = 256;
    const int grid = (total + block - 1) / block;   // 1728
    resize2d_kernel<<<grid, block, 0, stream>>>(in, out);
}